// Round 2
// baseline (604.858 us; speedup 1.0000x reference)
//
#include <hip/hip_runtime.h>

#define L_IN   4000
#define CIN    512
#define KSZ    16
#define LOUT   31992   // 8 * 3999
#define NQ     3999    // valid q: 0..3998
#define CCH    32      // ci rows per block (16 ci-chunks)

// Grid (16 ci-chunks, 16 b) = 256 blocks of 1024 threads (16 waves), 1/CU.
// ROLE SWAP vs previous rounds: each WAVE owns a 256-q subtile (qb = 256*wave
// + 4*lane) and LOOPS over the block's 32 ci rows. The 16 waves of a block
// therefore read CONSECUTIVE 1 KB chunks of the SAME row -> full 16 KB rows,
// and adjacent ci rows are adjacent in memory -> each block streams one fully
// CONTIGUOUS 512 KB region of x (the fill pattern that measures 6.9 TB/s),
// instead of 1 KB bursts at 16 KB stride (~3.1 TB/s wall, R0/R1 evidence).
// No barriers in the main loop: waves are fully independent; weights (2 KB)
// are staged once and read wave-uniform (ds_read_b128 broadcast).
// Each wave's outputs are complete in q but partial over the 16 ci-chunks:
// accumulate with fire-and-forget f32 global atomics (order-independent sum,
// 16 commutative addends) into the memset-zeroed output.
__global__ __launch_bounds__(1024, 4)
void dereverb_kernel(const float* __restrict__ x,
                     const float* __restrict__ t60s,
                     const float* __restrict__ kw,
                     float* __restrict__ out)
{
    __shared__ float wlds[CCH * KSZ];   // 2 KB

    const int c0   = blockIdx.x * CCH;
    const int b    = blockIdx.y;
    const int tid  = threadIdx.x;
    const int lane = tid & 63;
    const int wave = tid >> 6;          // 0..15 = q-subtile index

    // Per-sample kernel index (uniform): jnp.round = RNE = rintf.
    float t60 = t60s[b & 7];
    int kidx = (int)rintf(t60 * 100.0f) - 10;
    kidx = __builtin_amdgcn_readfirstlane(kidx);

    // Stage this block's 32x16 weights (2 KB): 128 float4 by threads 0..127.
    if (tid < 128)
        ((float4*)wlds)[tid] =
            ((const float4*)(kw + ((size_t)kidx * CIN + c0) * KSZ))[tid];
    __syncthreads();

    // Lane's q base; clamps keep all loads inside the current row.
    const int qb  = wave * 256 + 4 * lane;          // 0..4092 (full row span)
    const int qbl = qb < 3996 ? qb : 3996;          // 16B-aligned float4 base
    const int qan = (qb + 4) < NQ ? (qb + 4) : NQ;  // halo x[q+4]

    const float* xrow = x + ((size_t)b * CIN + c0) * L_IN;
    const float* xp = xrow + qbl;
    const float* xq = xrow + qan;
    const float4* wl = (const float4*)wlds;

    float acc[4][8];
    #pragma unroll
    for (int qi = 0; qi < 4; ++qi)
        #pragma unroll
        for (int r = 0; r < 8; ++r) acc[qi][r] = 0.0f;

#define FMA_BODY(A, AN, W0, W1, W2, W3) do {                        \
        const float xl[4] = {(A).x, (A).y, (A).z, (A).w};           \
        const float xh[4] = {(A).y, (A).z, (A).w, (AN)};            \
        const float wa[8] = {(W0).x,(W0).y,(W0).z,(W0).w,           \
                             (W1).x,(W1).y,(W1).z,(W1).w};          \
        const float wb[8] = {(W2).x,(W2).y,(W2).z,(W2).w,           \
                             (W3).x,(W3).y,(W3).z,(W3).w};          \
        _Pragma("unroll")                                           \
        for (int qi = 0; qi < 4; ++qi)                              \
            _Pragma("unroll")                                       \
            for (int r = 0; r < 8; ++r) {                           \
                acc[qi][r] = fmaf(xh[qi], wa[r], acc[qi][r]);       \
                acc[qi][r] = fmaf(xl[qi], wb[r], acc[qi][r]);       \
            }                                                       \
    } while (0)

    // Software-pipelined loop over the block's 32 ci rows (d=2 global, d=1 LDS).
    float4 a0 = *(const float4*)xp;
    float  n0 = *xq;
    float4 a1 = *(const float4*)(xp + L_IN);
    float  n1 = *(xq + L_IN);
    float4 w0 = wl[0], w1 = wl[1], w2 = wl[2], w3 = wl[3];

    #pragma unroll 2
    for (int ci = 0; ci < 30; ++ci) {
        float4 a2 = *(const float4*)(xp + 2 * L_IN);   // next-next row
        float  n2 = *(xq + 2 * L_IN);
        float4 u0 = wl[4], u1 = wl[5], u2 = wl[6], u3 = wl[7];
        FMA_BODY(a0, n0, w0, w1, w2, w3);
        a0 = a1; n0 = n1; a1 = a2; n1 = n2;
        w0 = u0; w1 = u1; w2 = u2; w3 = u3;
        xp += L_IN; xq += L_IN; wl += 4;
    }
    {   // ci = 30: last weight prefetch; x(31) already in a1/n1
        float4 u0 = wl[4], u1 = wl[5], u2 = wl[6], u3 = wl[7];
        FMA_BODY(a0, n0, w0, w1, w2, w3);
        a0 = a1; n0 = n1;
        w0 = u0; w1 = u1; w2 = u2; w3 = u3;
    }
    FMA_BODY(a0, n0, w0, w1, w2, w3);   // ci = 31

    // Epilogue: accumulate this ci-chunk's partials. Thread's 32 outputs are
    // 32 CONSECUTIVE floats [8*qb, 8*qb+32) of out[b] (2-line locality per
    // thread). Invalid q (> 3998, incl. clamped lanes) are skipped entirely.
    float* op = out + (size_t)b * LOUT + (size_t)8 * qb;
    #pragma unroll
    for (int qi = 0; qi < 4; ++qi)
        if (qb + qi <= NQ - 1)
            #pragma unroll
            for (int r = 0; r < 8; ++r)
                unsafeAtomicAdd(op + 8 * qi + r, acc[qi][r]);
#undef FMA_BODY
}

extern "C" void kernel_launch(void* const* d_in, const int* in_sizes, int n_in,
                              void* d_out, int out_size, void* d_ws, size_t ws_size,
                              hipStream_t stream) {
    const float* x    = (const float*)d_in[0];   // (16, 512, 4000)
    const float* t60s = (const float*)d_in[1];   // (8,)
    const float* kw   = (const float*)d_in[2];   // (41, 512, 1, 16)
    float* out = (float*)d_out;                  // (16, 1, 31992)

    // Zero-init for the 16-way ci-chunk atomic accumulation (graph-capturable).
    hipMemsetAsync(d_out, 0, out_size, stream);

    dim3 grid(CIN / CCH, 16);                    // (16 ci-chunks, 16 b) = 256
    dereverb_kernel<<<grid, 1024, 0, stream>>>(x, t60s, kw, out);
}

// Round 3
// 204.808 us; speedup vs baseline: 2.9533x; 2.9533x over previous
//
#include <hip/hip_runtime.h>

#define L_IN     4000
#define CIN      512
#define KSZ      16
#define LOUT     31992   // 8 * 3999
#define NQ       3999    // valid q: 0..3998
#define CCH      32      // ci rows per block (16 ci-chunks)
#define LOUT_PAD 32768   // per-partial slice: 8*4096 floats, pad swallows invalid q
#define NCH      16      // number of ci-chunks (= partials per output)
#define WS_FLOATS ((size_t)NCH * 16 * LOUT_PAD)   // 32 MB of workspace

// ---------------------------------------------------------------------------
// Stream kernel: grid (16 ci-chunks, 16 b) = 256 blocks of 1024 threads.
// Each WAVE owns a 256-q subtile (qb = 256*wave + 4*lane) and loops over the
// block's 32 ci rows, so the block streams one fully CONTIGUOUS 512 KB region
// of x (the access pattern that measures 6.9 TB/s on the harness fills; R2's
// FETCH_SIZE=64MB also showed it goes ~50% L3-resident across iterations).
// R2's fatal flaw -- 8.2M fp32 global atomics (262 MB of RMW sector traffic,
// 468 us) -- is replaced by plain coalesced float4 partial stores into a
// 32 MB workspace; a tiny reduce kernel folds the 16 ci-chunk partials.
// Slices are padded to 32768 floats: lanes with q > 3998 (clamped loads,
// finite garbage) store into tl >= 31992, which the reduce kernel never
// reads -- no masking, no zeroing, no memset needed.
// ---------------------------------------------------------------------------
__global__ __launch_bounds__(1024, 4)
void dereverb_stream(const float* __restrict__ x,
                     const float* __restrict__ t60s,
                     const float* __restrict__ kw,
                     float* __restrict__ ws)
{
    __shared__ float wlds[CCH * KSZ];   // 2 KB

    const int c0   = blockIdx.x * CCH;
    const int b    = blockIdx.y;
    const int tid  = threadIdx.x;
    const int lane = tid & 63;
    const int wave = tid >> 6;          // 0..15 = q-subtile index

    // Per-sample kernel index (uniform): jnp.round = RNE = rintf.
    float t60 = t60s[b & 7];
    int kidx = (int)rintf(t60 * 100.0f) - 10;
    kidx = __builtin_amdgcn_readfirstlane(kidx);

    // Stage this block's 32x16 weights (2 KB): 128 float4 by threads 0..127.
    if (tid < 128)
        ((float4*)wlds)[tid] =
            ((const float4*)(kw + ((size_t)kidx * CIN + c0) * KSZ))[tid];
    __syncthreads();

    // Lane's q base; clamps keep all loads inside the current row.
    const int qb  = wave * 256 + 4 * lane;          // 0..4092 (full row span)
    const int qbl = qb < 3996 ? qb : 3996;          // 16B-aligned float4 base
    const int qan = (qb + 4) < NQ ? (qb + 4) : NQ;  // halo x[q+4]

    const float* xrow = x + ((size_t)b * CIN + c0) * L_IN;
    const float* xp = xrow + qbl;
    const float* xq = xrow + qan;
    const float4* wl = (const float4*)wlds;

    float acc[4][8];
    #pragma unroll
    for (int qi = 0; qi < 4; ++qi)
        #pragma unroll
        for (int r = 0; r < 8; ++r) acc[qi][r] = 0.0f;

#define FMA_BODY(A, AN, W0, W1, W2, W3) do {                        \
        const float xl[4] = {(A).x, (A).y, (A).z, (A).w};           \
        const float xh[4] = {(A).y, (A).z, (A).w, (AN)};            \
        const float wa[8] = {(W0).x,(W0).y,(W0).z,(W0).w,           \
                             (W1).x,(W1).y,(W1).z,(W1).w};          \
        const float wb[8] = {(W2).x,(W2).y,(W2).z,(W2).w,           \
                             (W3).x,(W3).y,(W3).z,(W3).w};          \
        _Pragma("unroll")                                           \
        for (int qi = 0; qi < 4; ++qi)                              \
            _Pragma("unroll")                                       \
            for (int r = 0; r < 8; ++r) {                           \
                acc[qi][r] = fmaf(xh[qi], wa[r], acc[qi][r]);       \
                acc[qi][r] = fmaf(xl[qi], wb[r], acc[qi][r]);       \
            }                                                       \
    } while (0)

    // Software-pipelined loop over the block's 32 ci rows (d=2 global, d=1 LDS).
    float4 a0 = *(const float4*)xp;
    float  n0 = *xq;
    float4 a1 = *(const float4*)(xp + L_IN);
    float  n1 = *(xq + L_IN);
    float4 w0 = wl[0], w1 = wl[1], w2 = wl[2], w3 = wl[3];

    #pragma unroll 2
    for (int ci = 0; ci < 30; ++ci) {
        float4 a2 = *(const float4*)(xp + 2 * L_IN);   // next-next row
        float  n2 = *(xq + 2 * L_IN);
        float4 u0 = wl[4], u1 = wl[5], u2 = wl[6], u3 = wl[7];
        FMA_BODY(a0, n0, w0, w1, w2, w3);
        a0 = a1; n0 = n1; a1 = a2; n1 = n2;
        w0 = u0; w1 = u1; w2 = u2; w3 = u3;
        xp += L_IN; xq += L_IN; wl += 4;
    }
    {   // ci = 30: last weight prefetch; x(31) already in a1/n1
        float4 u0 = wl[4], u1 = wl[5], u2 = wl[6], u3 = wl[7];
        FMA_BODY(a0, n0, w0, w1, w2, w3);
        a0 = a1; n0 = n1;
        w0 = u0; w1 = u1; w2 = u2; w3 = u3;
    }
    FMA_BODY(a0, n0, w0, w1, w2, w3);   // ci = 31

    // Epilogue: plain coalesced partial stores. Thread's 32 consecutive
    // floats start at 8*qb = 2048*wave + 32*lane -> each wave writes
    // contiguous 2 KB per float4 column, fully coalesced. Invalid q lands
    // in the slice pad [31992, 32768).
    float* op = ws + (size_t)(blockIdx.x * 16 + b) * LOUT_PAD + (size_t)8 * qb;
    #pragma unroll
    for (int qi = 0; qi < 4; ++qi) {
        float4 lo = {acc[qi][0], acc[qi][1], acc[qi][2], acc[qi][3]};
        float4 hi = {acc[qi][4], acc[qi][5], acc[qi][6], acc[qi][7]};
        ((float4*)(op + 8 * qi))[0] = lo;
        ((float4*)(op + 8 * qi))[1] = hi;
    }
#undef FMA_BODY
}

// ---------------------------------------------------------------------------
// Reduce kernel: out[b][t] = sum_c ws[c*16+b][t]. Grid (32, 16b) x 256 thr;
// each thread sums 16 float4 addends at 16*LOUT_PAD stride (every stream
// coalesced across lanes), 2 blocks/CU. Traffic: 32 MB read + 2 MB write.
// ---------------------------------------------------------------------------
__global__ __launch_bounds__(256, 8)
void dereverb_reduce(const float* __restrict__ ws, float* __restrict__ out)
{
    const int b  = blockIdx.y;
    const int t4 = blockIdx.x * 256 + threadIdx.x;   // float4 index in [0, 7998)
    if (t4 >= LOUT / 4) return;

    const float4* p = (const float4*)(ws + (size_t)b * LOUT_PAD) + t4;
    float4 s = {0.0f, 0.0f, 0.0f, 0.0f};
    #pragma unroll
    for (int c = 0; c < NCH; ++c) {
        float4 v = *p;
        s.x += v.x; s.y += v.y; s.z += v.z; s.w += v.w;
        p += (size_t)16 * LOUT_PAD / 4;
    }
    ((float4*)(out + (size_t)b * LOUT))[t4] = s;
}

// ---------------------------------------------------------------------------
// Fallback (ws too small): the R0 single-kernel version -- 195 us known-good,
// no workspace, no atomics, no memset.
// ---------------------------------------------------------------------------
#define QPB 256
#define RST 1088
__global__ __launch_bounds__(1024, 4)
void dereverb_fallback(const float* __restrict__ x,
                       const float* __restrict__ t60s,
                       const float* __restrict__ kw,
                       float* __restrict__ out)
{
    __shared__ float lds[8 * RST];

    const int b    = blockIdx.y;
    const int q0   = blockIdx.x * QPB;
    const int tid  = threadIdx.x;
    const int lane = tid & 63;
    const int wave = tid >> 6;

    float t60 = t60s[b & 7];
    int kidx = (int)rintf(t60 * 100.0f) - 10;
    kidx = __builtin_amdgcn_readfirstlane(kidx);
    const float4* wsrc = (const float4*)(kw + (size_t)kidx * (CIN * KSZ));

    ((float4*)lds)[tid]        = wsrc[tid];
    ((float4*)lds)[tid + 1024] = wsrc[tid + 1024];
    __syncthreads();

    const int qb  = q0 + 4 * lane;
    const int qbl = qb < 3996 ? qb : 3996;
    const int qan = (qb + 4) < NQ ? (qb + 4) : NQ;

    const float* xr = x + ((size_t)b * CIN + wave * 32) * L_IN;
    const float* xp = xr + qbl;
    const float* xq = xr + qan;
    const float4* wl = (const float4*)(lds + wave * 32 * KSZ);

    float acc[4][8];
    #pragma unroll
    for (int qi = 0; qi < 4; ++qi)
        #pragma unroll
        for (int r = 0; r < 8; ++r) acc[qi][r] = 0.0f;

    #pragma unroll 4
    for (int ci = 0; ci < 32; ++ci) {
        float4 a  = *(const float4*)xp;
        float  an = *xq;
        xp += L_IN;
        xq += L_IN;

        float4 wv[4];
        wv[0] = wl[0]; wv[1] = wl[1]; wv[2] = wl[2]; wv[3] = wl[3];
        wl += 4;
        const float* wf = (const float*)wv;

        const float x0v[4] = {a.x, a.y, a.z, a.w};
        const float x1v[4] = {a.y, a.z, a.w, an};
        #pragma unroll
        for (int qi = 0; qi < 4; ++qi)
            #pragma unroll
            for (int r = 0; r < 8; ++r) {
                acc[qi][r] = fmaf(x1v[qi], wf[r],     acc[qi][r]);
                acc[qi][r] = fmaf(x0v[qi], wf[r + 8], acc[qi][r]);
            }
    }

    #pragma unroll
    for (int qi = 0; qi < 4; ++qi)
        if (qb + qi > NQ - 1)
            #pragma unroll
            for (int r = 0; r < 8; ++r) acc[qi][r] = 0.0f;

    const size_t obase = (size_t)b * LOUT + (size_t)q0 * 8;
    #pragma unroll
    for (int p = 0; p < 2; ++p) {
        __syncthreads();
        if (wave >= 8) {
            float* rp = lds + (wave - 8) * RST + lane * 17;
            #pragma unroll
            for (int qih = 0; qih < 2; ++qih)
                #pragma unroll
                for (int r = 0; r < 8; ++r)
                    rp[qih * 8 + r] = acc[2 * p + qih][r];
        }
        __syncthreads();
        if (wave < 8) {
            float* rp = lds + wave * RST + lane * 17;
            #pragma unroll
            for (int qih = 0; qih < 2; ++qih)
                #pragma unroll
                for (int r = 0; r < 8; ++r)
                    rp[qih * 8 + r] += acc[2 * p + qih][r];
        }
        __syncthreads();
        int k = tid >> 4, j = tid & 15;
        int tl = 32 * k + 16 * p + j;
        if (q0 * 8 + tl < LOUT) {
            float s = 0.0f;
            #pragma unroll
            for (int w = 0; w < 8; ++w)
                s += lds[w * RST + k * 17 + j];
            out[obase + tl] = s;
        }
    }
}

extern "C" void kernel_launch(void* const* d_in, const int* in_sizes, int n_in,
                              void* d_out, int out_size, void* d_ws, size_t ws_size,
                              hipStream_t stream) {
    const float* x    = (const float*)d_in[0];   // (16, 512, 4000)
    const float* t60s = (const float*)d_in[1];   // (8,)
    const float* kw   = (const float*)d_in[2];   // (41, 512, 1, 16)
    float* out = (float*)d_out;                  // (16, 1, 31992)

    if (ws_size >= WS_FLOATS * sizeof(float) && d_ws != nullptr) {
        float* ws = (float*)d_ws;
        dim3 g1(CIN / CCH, 16);                  // (16 ci-chunks, 16 b) = 256
        dereverb_stream<<<g1, 1024, 0, stream>>>(x, t60s, kw, ws);
        dim3 g2((LOUT / 4 + 255) / 256, 16);     // (32, 16) = 512
        dereverb_reduce<<<g2, 256, 0, stream>>>(ws, out);
    } else {
        dim3 grid((NQ + QPB - 1) / QPB, 16);     // (16, 16)
        dereverb_fallback<<<grid, 1024, 0, stream>>>(x, t60s, kw, out);
    }
}